// Round 14
// baseline (139.572 us; speedup 1.0000x reference)
//
#include <hip/hip_runtime.h>
#include <math.h>

#define H 128
#define NF 100000
#define NC 25000

typedef _Float16 f16;
typedef f16 f16x8 __attribute__((ext_vector_type(8)));
typedef float f32x4 __attribute__((ext_vector_type(4)));

#define MFMA16(a, b, c) __builtin_amdgcn_mfma_f32_16x16x32_f16((a), (b), (c), 0, 0, 0)

// ws: fragment-ordered f16 weights (fragment = 64 lanes x 8 f16 = 1 KB contiguous)
//   F1 @ 0     : [nt=8][kk=8][lane=64][8]   W1^T, k<256 (kk 0..3 = xg half, 4..7 = xs half)
//   F2 @ 32768 : [nt=8][kk=4][lane=64][8]   W2^T
//   F3 @ 49152 : [nt=8][kk=4][lane=64][8]   W3^T
// fragment element: n = nt*16 + (lane&15), k = kk*32 + (lane>>4)*8 + j

__global__ void prep_w(const float* __restrict__ W1, const float* __restrict__ W2,
                       const float* __restrict__ W3, f16* __restrict__ ws)
{
    int i = blockIdx.x * 256 + threadIdx.x;   // 0..65535, grid exact
    if (i < 32768) {
        int j = i & 7, lane = (i >> 3) & 63, kk = (i >> 9) & 7, nt = i >> 12;
        int n = nt * 16 + (lane & 15);
        int k = kk * 32 + (lane >> 4) * 8 + j;
        ws[i] = (f16)W1[k * H + n];
    } else if (i < 49152) {
        int q = i - 32768;
        int j = q & 7, lane = (q >> 3) & 63, kk = (q >> 9) & 3, nt = q >> 11;
        int n = nt * 16 + (lane & 15);
        int k = kk * 32 + (lane >> 4) * 8 + j;
        ws[i] = (f16)W2[k * H + n];
    } else {
        int q = i - 49152;
        int j = q & 7, lane = (q >> 3) & 63, kk = (q >> 9) & 3, nt = q >> 11;
        int n = nt * 16 + (lane & 15);
        int k = kk * 32 + (lane >> 4) * 8 + j;
        ws[i] = (f16)W3[k * H + n];
    }
}

__device__ __forceinline__ float silu_f(float v) {
    return v / (1.0f + __expf(-v));
}

// convert 8 f32 (two float4) to an f16x8 fragment
__device__ __forceinline__ f16x8 cvt8(float4 v0, float4 v1) {
    f16x8 r;
    r[0] = (f16)v0.x; r[1] = (f16)v0.y; r[2] = (f16)v0.z; r[3] = (f16)v0.w;
    r[4] = (f16)v1.x; r[5] = (f16)v1.y; r[6] = (f16)v1.z; r[7] = (f16)v1.w;
    return r;
}

// ZERO-BARRIER kernel: each wave owns 32 rows x 128 cols with a private 8 KB
// LDS slice ([32][128] f16, 16B-slot XOR swizzle). Wave-internal LDS ordering
// (in-order DS unit + compiler lgkmcnt) replaces all __syncthreads.
// Block = 128 threads (2 independent waves). NF % 32 == 0: no batch straddle.
__global__ __launch_bounds__(128, 3)
void fused_mlp_v14(const float* __restrict__ x,     // [2][25000][128]
                   const float* __restrict__ xsc,   // [2][100000][128]
                   const int*   __restrict__ f2c,   // [100000]
                   const float* __restrict__ dist,  // [100000]
                   const float* __restrict__ W1,    // [257][128] (row 256 used as f32)
                   const float* __restrict__ b1,
                   const float* __restrict__ b2,
                   const float* __restrict__ b3,
                   const f16*   __restrict__ ws,
                   float* __restrict__ out)         // [200000][128]
{
    __shared__ __align__(16) f16 sX[2 * 32 * H];     // 16 KB, 8 KB per wave

    const int t = threadIdx.x;
    const int l = t & 63, wid = t >> 6;
    const int lr = l & 15, lg = l >> 4;
    const int srow = l >> 4;                         // staging row-in-group 0..3
    const int ss   = lr;                             // staging 16B slot 0..15

    const int R0w   = blockIdx.x * 64 + wid * 32;    // wave's base row
    const int bb    = R0w >= NF;
    const int fbase = R0w - bb * NF;                 // fine-index base (mult of 32)

    f16* sW = sX + wid * (32 * H);

    const f16* F1 = ws;
    const f16* F2 = ws + 32768;
    const f16* F3 = ws + 49152;

    // ---- stage xg (gathered coarse rows), coalesced 512 B/row ----
    #pragma unroll
    for (int i = 0; i < 8; ++i) {
        int row = i * 4 + srow;                      // 0..31
        int ci  = f2c[fbase + row];
        const float* src = x + (long long)(bb * NC + ci) * H + ss * 8;
        f16x8 v = cvt8(*(const float4*)src, *(const float4*)(src + 4));
        *(f16x8*)(sW + row * H + ((ss ^ (row & 7)) << 3)) = v;
    }

    // ---- acc init: b1 + d*W1[256] ----
    f32x4 acc[2][8];
    float dd[2][4];
    #pragma unroll
    for (int mt = 0; mt < 2; ++mt) {
        float4 dv = *(const float4*)(dist + fbase + mt * 16 + lg * 4);
        dd[mt][0] = dv.x; dd[mt][1] = dv.y; dd[mt][2] = dv.z; dd[mt][3] = dv.w;
    }
    #pragma unroll
    for (int nt = 0; nt < 8; ++nt) {
        int col = nt * 16 + lr;
        float bc = b1[col];
        float wc = W1[256 * H + col];
        #pragma unroll
        for (int mt = 0; mt < 2; ++mt)
            #pragma unroll
            for (int r = 0; r < 4; ++r)
                acc[mt][nt][r] = bc + dd[mt][r] * wc;
    }

    // ---- layer 1, xg half (F1 kk=0..3) ----
    #pragma unroll
    for (int kk = 0; kk < 4; ++kk) {
        int s = kk * 4 + lg;
        f16x8 a0 = *(const f16x8*)(sW + lr * H + ((s ^ (lr & 7)) << 3));
        f16x8 a1 = *(const f16x8*)(sW + (16 + lr) * H + ((s ^ (lr & 7)) << 3));
        #pragma unroll
        for (int nt = 0; nt < 8; ++nt) {
            f16x8 wv = *(const f16x8*)(F1 + (((nt * 8 + kk) * 64 + l) << 3));
            acc[0][nt] = MFMA16(a0, wv, acc[0][nt]);
            acc[1][nt] = MFMA16(a1, wv, acc[1][nt]);
        }
    }

    // ---- restage xs into the same slice (wave-internal ordering) ----
    #pragma unroll
    for (int i = 0; i < 8; ++i) {
        int row = i * 4 + srow;
        const float* src = xsc + (long long)(R0w + row) * H + ss * 8;
        f16x8 v = cvt8(*(const float4*)src, *(const float4*)(src + 4));
        *(f16x8*)(sW + row * H + ((ss ^ (row & 7)) << 3)) = v;
    }

    // ---- layer 1, xs half (F1 kk=4..7) ----
    #pragma unroll
    for (int kk = 0; kk < 4; ++kk) {
        int s = kk * 4 + lg;
        f16x8 a0 = *(const f16x8*)(sW + lr * H + ((s ^ (lr & 7)) << 3));
        f16x8 a1 = *(const f16x8*)(sW + (16 + lr) * H + ((s ^ (lr & 7)) << 3));
        #pragma unroll
        for (int nt = 0; nt < 8; ++nt) {
            f16x8 wv = *(const f16x8*)(F1 + (((nt * 8 + kk + 4) * 64 + l) << 3));
            acc[0][nt] = MFMA16(a0, wv, acc[0][nt]);
            acc[1][nt] = MFMA16(a1, wv, acc[1][nt]);
        }
    }

    // ---- h1 -> own slice (silu + f16, swizzled) ----
    #pragma unroll
    for (int nt = 0; nt < 8; ++nt)
        #pragma unroll
        for (int mt = 0; mt < 2; ++mt)
            #pragma unroll
            for (int r = 0; r < 4; ++r) {
                int row = mt * 16 + lg * 4 + r;
                int col = nt * 16 + lr;
                sW[row * H + (((col >> 3) ^ (row & 7)) << 3) + (col & 7)] =
                    (f16)silu_f(acc[mt][nt][r]);
            }

    // ---- layer 2 ----
    #pragma unroll
    for (int nt = 0; nt < 8; ++nt) {
        float bc = b2[nt * 16 + lr];
        #pragma unroll
        for (int mt = 0; mt < 2; ++mt)
            #pragma unroll
            for (int r = 0; r < 4; ++r)
                acc[mt][nt][r] = bc;
    }
    #pragma unroll
    for (int kk = 0; kk < 4; ++kk) {
        int s = kk * 4 + lg;
        f16x8 a0 = *(const f16x8*)(sW + lr * H + ((s ^ (lr & 7)) << 3));
        f16x8 a1 = *(const f16x8*)(sW + (16 + lr) * H + ((s ^ (lr & 7)) << 3));
        #pragma unroll
        for (int nt = 0; nt < 8; ++nt) {
            f16x8 wv = *(const f16x8*)(F2 + (((nt * 4 + kk) * 64 + l) << 3));
            acc[0][nt] = MFMA16(a0, wv, acc[0][nt]);
            acc[1][nt] = MFMA16(a1, wv, acc[1][nt]);
        }
    }

    // ---- h2 -> own slice ----
    #pragma unroll
    for (int nt = 0; nt < 8; ++nt)
        #pragma unroll
        for (int mt = 0; mt < 2; ++mt)
            #pragma unroll
            for (int r = 0; r < 4; ++r) {
                int row = mt * 16 + lg * 4 + r;
                int col = nt * 16 + lr;
                sW[row * H + (((col >> 3) ^ (row & 7)) << 3) + (col & 7)] =
                    (f16)silu_f(acc[mt][nt][r]);
            }

    // ---- layer 3 ----
    #pragma unroll
    for (int nt = 0; nt < 8; ++nt) {
        float bc = b3[nt * 16 + lr];
        #pragma unroll
        for (int mt = 0; mt < 2; ++mt)
            #pragma unroll
            for (int r = 0; r < 4; ++r)
                acc[mt][nt][r] = bc;
    }
    #pragma unroll
    for (int kk = 0; kk < 4; ++kk) {
        int s = kk * 4 + lg;
        f16x8 a0 = *(const f16x8*)(sW + lr * H + ((s ^ (lr & 7)) << 3));
        f16x8 a1 = *(const f16x8*)(sW + (16 + lr) * H + ((s ^ (lr & 7)) << 3));
        #pragma unroll
        for (int nt = 0; nt < 8; ++nt) {
            f16x8 wv = *(const f16x8*)(F3 + (((nt * 4 + kk) * 64 + l) << 3));
            acc[0][nt] = MFMA16(a0, wv, acc[0][nt]);
            acc[1][nt] = MFMA16(a1, wv, acc[1][nt]);
        }
    }

    // ---- store out ----
    #pragma unroll
    for (int mt = 0; mt < 2; ++mt)
        #pragma unroll
        for (int nt = 0; nt < 8; ++nt)
            #pragma unroll
            for (int r = 0; r < 4; ++r) {
                long long row = (long long)R0w + mt * 16 + lg * 4 + r;
                int col = nt * 16 + lr;
                out[row * H + col] = acc[mt][nt][r];
            }
}

extern "C" void kernel_launch(void* const* d_in, const int* in_sizes, int n_in,
                              void* d_out, int out_size, void* d_ws, size_t ws_size,
                              hipStream_t stream)
{
    const float* x    = (const float*)d_in[0];
    const float* xsc  = (const float*)d_in[1];
    const int*   f2c  = (const int*)d_in[2];
    const float* dist = (const float*)d_in[3];
    const float* W1   = (const float*)d_in[4];
    const float* b1   = (const float*)d_in[5];
    const float* W2   = (const float*)d_in[6];
    const float* b2   = (const float*)d_in[7];
    const float* W3   = (const float*)d_in[8];
    const float* b3   = (const float*)d_in[9];
    f16* ws = (f16*)d_ws;

    prep_w<<<256, 256, 0, stream>>>(W1, W2, W3, ws);

    const int n_rows = 2 * NF;                    // 200000
    dim3 grid(n_rows / 64);                       // 3125 blocks x 2 independent waves
    fused_mlp_v14<<<grid, 128, 0, stream>>>(x, xsc, f2c, dist, W1, b1, b2, b3,
                                            ws, (float*)d_out);
}

// Round 15
// 95.476 us; speedup vs baseline: 1.4619x; 1.4619x over previous
//
#include <hip/hip_runtime.h>
#include <math.h>

#define H 128
#define NF 100000
#define NC 25000
#define TM 64

typedef _Float16 f16;
typedef f16 f16x8 __attribute__((ext_vector_type(8)));
typedef f16 f16x4 __attribute__((ext_vector_type(4)));
typedef float f32x4 __attribute__((ext_vector_type(4)));

#define MFMA16(a, b, c) __builtin_amdgcn_mfma_f32_16x16x32_f16((a), (b), (c), 0, 0, 0)

// ws: fragment-ordered f16 weights (fragment = 64 lanes x 8 f16 = 1 KB contiguous)
//   F1 @ 0     : [nt=8][kk=8][lane=64][8]   W1^T, k<256 (kk 0..3 = xg half, 4..7 = xs half)
//   F2 @ 32768 : [nt=8][kk=4][lane=64][8]   W2^T
//   F3 @ 49152 : [nt=8][kk=4][lane=64][8]   W3^T
// fragment element: n = nt*16 + (lane&15), k = kk*32 + (lane>>4)*8 + j

__global__ void prep_w(const float* __restrict__ W1, const float* __restrict__ W2,
                       const float* __restrict__ W3, f16* __restrict__ ws)
{
    int i = blockIdx.x * 256 + threadIdx.x;   // 0..65535, grid exact
    if (i < 32768) {
        int j = i & 7, lane = (i >> 3) & 63, kk = (i >> 9) & 7, nt = i >> 12;
        int n = nt * 16 + (lane & 15);
        int k = kk * 32 + (lane >> 4) * 8 + j;
        ws[i] = (f16)W1[k * H + n];
    } else if (i < 49152) {
        int q = i - 32768;
        int j = q & 7, lane = (q >> 3) & 63, kk = (q >> 9) & 3, nt = q >> 11;
        int n = nt * 16 + (lane & 15);
        int k = kk * 32 + (lane >> 4) * 8 + j;
        ws[i] = (f16)W2[k * H + n];
    } else {
        int q = i - 49152;
        int j = q & 7, lane = (q >> 3) & 63, kk = (q >> 9) & 3, nt = q >> 11;
        int n = nt * 16 + (lane & 15);
        int k = kk * 32 + (lane >> 4) * 8 + j;
        ws[i] = (f16)W3[k * H + n];
    }
}

__device__ __forceinline__ float silu_f(float v) {
    return v / (1.0f + __expf(-v));
}

// R11 structure + deep register prefetch of F2/F3 weight fragments.
// launch_bounds(256,3): VGPR cap ~170, 3 blocks/CU (= achieved occupancy anyway).
__global__ __launch_bounds__(256, 3)
void fused_mlp_v15(const float* __restrict__ x,     // [2][25000][128]
                   const float* __restrict__ xsc,   // [2][100000][128]
                   const int*   __restrict__ f2c,   // [100000]
                   const float* __restrict__ dist,  // [100000]
                   const float* __restrict__ W1,    // [257][128] (row 256 used as f32)
                   const float* __restrict__ b1,
                   const float* __restrict__ b2,
                   const float* __restrict__ b3,
                   const f16*   __restrict__ ws,
                   float* __restrict__ out)         // [200000][128]
{
    __shared__ __align__(16) f16 sA[TM * H];         // 16 KB
    __shared__ float sD[TM];
    __shared__ int   sCI[TM];

    const int t = threadIdx.x;
    const int l = t & 63, w = t >> 6;
    const int wRow = (w >> 1) * 32;                  // 0 or 32
    const int wnt  = (w & 1) * 4;                    // first n-tile (of 8) for this wave
    const int lr = l & 15, lg = l >> 4;
    const int R0 = blockIdx.x * TM;

    const f16* F1 = ws;
    const f16* F2 = ws + 32768;
    const f16* F3 = ws + 49152;

    // ---- PREFETCH F2 (16 fragments, 64 VGPR) — issued first, consumed in layer 2 ----
    f16x8 wv2_00, wv2_01, wv2_02, wv2_03;
    f16x8 wv2_10, wv2_11, wv2_12, wv2_13;
    f16x8 wv2_20, wv2_21, wv2_22, wv2_23;
    f16x8 wv2_30, wv2_31, wv2_32, wv2_33;
    {
        const f16* base = F2 + ((wnt * 4 * 64 + l) << 3);
        // frag(kk,nt) at (((wnt+nt)*4 + kk)*64 + l)*8
        wv2_00 = *(const f16x8*)(base + ((0 * 64) << 3));
        wv2_01 = *(const f16x8*)(base + ((4 * 64) << 3));
        wv2_02 = *(const f16x8*)(base + ((8 * 64) << 3));
        wv2_03 = *(const f16x8*)(base + ((12 * 64) << 3));
        wv2_10 = *(const f16x8*)(base + ((1 * 64) << 3));
        wv2_11 = *(const f16x8*)(base + ((5 * 64) << 3));
        wv2_12 = *(const f16x8*)(base + ((9 * 64) << 3));
        wv2_13 = *(const f16x8*)(base + ((13 * 64) << 3));
        wv2_20 = *(const f16x8*)(base + ((2 * 64) << 3));
        wv2_21 = *(const f16x8*)(base + ((6 * 64) << 3));
        wv2_22 = *(const f16x8*)(base + ((10 * 64) << 3));
        wv2_23 = *(const f16x8*)(base + ((14 * 64) << 3));
        wv2_30 = *(const f16x8*)(base + ((3 * 64) << 3));
        wv2_31 = *(const f16x8*)(base + ((7 * 64) << 3));
        wv2_32 = *(const f16x8*)(base + ((11 * 64) << 3));
        wv2_33 = *(const f16x8*)(base + ((15 * 64) << 3));
    }

    // ---- per-row metadata ----
    if (t < TM) {
        int Rs = R0 + t;
        int bb = Rs >= NF;
        int nn = Rs - bb * NF;
        sCI[t] = bb * NC + f2c[nn];
        sD[t]  = dist[nn];
    }
    __syncthreads();                                 // B0 (prefetch can't sink past)

    // ---- acc init: b1 + d*W1[256] ----
    f32x4 acc[2][4];
    #pragma unroll
    for (int nt = 0; nt < 4; ++nt) {
        int col = (wnt + nt) * 16 + lr;
        float bc = b1[col];
        float wc = W1[256 * H + col];
        #pragma unroll
        for (int mt = 0; mt < 2; ++mt)
            #pragma unroll
            for (int r = 0; r < 4; ++r)
                acc[mt][nt][r] = bc + sD[wRow + mt * 16 + lg * 4 + r] * wc;
    }

    // ---- phase 1: stage xg (gathered coarse rows) ----
    #pragma unroll
    for (int i = 0; i < 8; ++i) {
        int f = i * 256 + t;
        int row = f >> 5, col = (f & 31) * 4;
        float4 v = *(const float4*)(x + (long long)sCI[row] * H + col);
        f16x4 hv; hv[0] = (f16)v.x; hv[1] = (f16)v.y; hv[2] = (f16)v.z; hv[3] = (f16)v.w;
        *(f16x4*)(sA + row * H + (((col >> 3) ^ (row & 7)) << 3) + (col & 7)) = hv;
    }
    __syncthreads();                                 // B1: xg ready

    // layer-1 half 0 (F1 kk=0..3), streamed with per-kk fragment window
    #pragma unroll
    for (int kk = 0; kk < 4; ++kk) {
        f16x8 wv[4];
        #pragma unroll
        for (int nt = 0; nt < 4; ++nt)
            wv[nt] = *(const f16x8*)(F1 + ((((wnt + nt) * 8 + kk) * 64 + l) << 3));
        int k = kk * 32 + (lg << 3);
        int slot = (((k >> 3) ^ (lr & 7)) << 3);
        f16x8 a0 = *(const f16x8*)(sA + (wRow + lr) * H + slot);
        f16x8 a1 = *(const f16x8*)(sA + (wRow + 16 + lr) * H + slot);
        #pragma unroll
        for (int nt = 0; nt < 4; ++nt) {
            acc[0][nt] = MFMA16(a0, wv[nt], acc[0][nt]);
            acc[1][nt] = MFMA16(a1, wv[nt], acc[1][nt]);
        }
    }
    __syncthreads();                                 // B2: xg reads done

    // ---- phase 2: stage xs into the same buffer ----
    #pragma unroll
    for (int i = 0; i < 8; ++i) {
        int f = i * 256 + t;
        int row = f >> 5, col = (f & 31) * 4;
        float4 v = *(const float4*)(xsc + (long long)(R0 + row) * H + col);
        f16x4 hv; hv[0] = (f16)v.x; hv[1] = (f16)v.y; hv[2] = (f16)v.z; hv[3] = (f16)v.w;
        *(f16x4*)(sA + row * H + (((col >> 3) ^ (row & 7)) << 3) + (col & 7)) = hv;
    }
    __syncthreads();                                 // B3: xs ready

    // layer-1 half 1 (F1 kk=4..7)
    #pragma unroll
    for (int kk = 0; kk < 4; ++kk) {
        f16x8 wv[4];
        #pragma unroll
        for (int nt = 0; nt < 4; ++nt)
            wv[nt] = *(const f16x8*)(F1 + ((((wnt + nt) * 8 + kk + 4) * 64 + l) << 3));
        int k = kk * 32 + (lg << 3);
        int slot = (((k >> 3) ^ (lr & 7)) << 3);
        f16x8 a0 = *(const f16x8*)(sA + (wRow + lr) * H + slot);
        f16x8 a1 = *(const f16x8*)(sA + (wRow + 16 + lr) * H + slot);
        #pragma unroll
        for (int nt = 0; nt < 4; ++nt) {
            acc[0][nt] = MFMA16(a0, wv[nt], acc[0][nt]);
            acc[1][nt] = MFMA16(a1, wv[nt], acc[1][nt]);
        }
    }
    __syncthreads();                                 // B4: xs reads done

    // h1 -> sA
    #pragma unroll
    for (int nt = 0; nt < 4; ++nt)
        #pragma unroll
        for (int mt = 0; mt < 2; ++mt)
            #pragma unroll
            for (int r = 0; r < 4; ++r) {
                int row = wRow + mt * 16 + lg * 4 + r;
                int col = (wnt + nt) * 16 + lr;
                sA[row * H + (((col >> 3) ^ (row & 7)) << 3) + (col & 7)] =
                    (f16)silu_f(acc[mt][nt][r]);
            }
    __syncthreads();                                 // B5: h1 ready

    // ---- layer 2: pure LDS + prefetched registers (no global latency) ----
    #pragma unroll
    for (int nt = 0; nt < 4; ++nt) {
        float bc = b2[(wnt + nt) * 16 + lr];
        #pragma unroll
        for (int mt = 0; mt < 2; ++mt)
            #pragma unroll
            for (int r = 0; r < 4; ++r)
                acc[mt][nt][r] = bc;
    }
    #pragma unroll
    for (int kk = 0; kk < 4; ++kk) {
        int k = kk * 32 + (lg << 3);
        int slot = (((k >> 3) ^ (lr & 7)) << 3);
        f16x8 a0 = *(const f16x8*)(sA + (wRow + lr) * H + slot);
        f16x8 a1 = *(const f16x8*)(sA + (wRow + 16 + lr) * H + slot);
        f16x8 w0 = (kk == 0) ? wv2_00 : (kk == 1) ? wv2_10 : (kk == 2) ? wv2_20 : wv2_30;
        f16x8 w1 = (kk == 0) ? wv2_01 : (kk == 1) ? wv2_11 : (kk == 2) ? wv2_21 : wv2_31;
        f16x8 w2 = (kk == 0) ? wv2_02 : (kk == 1) ? wv2_12 : (kk == 2) ? wv2_22 : wv2_32;
        f16x8 w3 = (kk == 0) ? wv2_03 : (kk == 1) ? wv2_13 : (kk == 2) ? wv2_23 : wv2_33;
        acc[0][0] = MFMA16(a0, w0, acc[0][0]);
        acc[1][0] = MFMA16(a1, w0, acc[1][0]);
        acc[0][1] = MFMA16(a0, w1, acc[0][1]);
        acc[1][1] = MFMA16(a1, w1, acc[1][1]);
        acc[0][2] = MFMA16(a0, w2, acc[0][2]);
        acc[1][2] = MFMA16(a1, w2, acc[1][2]);
        acc[0][3] = MFMA16(a0, w3, acc[0][3]);
        acc[1][3] = MFMA16(a1, w3, acc[1][3]);
    }
    __syncthreads();                                 // B6: h1 reads done

    // ---- PREFETCH F3 (reuses wv2's dead registers), lands under h2 writeback ----
    f16x8 wv3_00, wv3_01, wv3_02, wv3_03;
    f16x8 wv3_10, wv3_11, wv3_12, wv3_13;
    f16x8 wv3_20, wv3_21, wv3_22, wv3_23;
    f16x8 wv3_30, wv3_31, wv3_32, wv3_33;
    {
        const f16* base = F3 + ((wnt * 4 * 64 + l) << 3);
        wv3_00 = *(const f16x8*)(base + ((0 * 64) << 3));
        wv3_01 = *(const f16x8*)(base + ((4 * 64) << 3));
        wv3_02 = *(const f16x8*)(base + ((8 * 64) << 3));
        wv3_03 = *(const f16x8*)(base + ((12 * 64) << 3));
        wv3_10 = *(const f16x8*)(base + ((1 * 64) << 3));
        wv3_11 = *(const f16x8*)(base + ((5 * 64) << 3));
        wv3_12 = *(const f16x8*)(base + ((9 * 64) << 3));
        wv3_13 = *(const f16x8*)(base + ((13 * 64) << 3));
        wv3_20 = *(const f16x8*)(base + ((2 * 64) << 3));
        wv3_21 = *(const f16x8*)(base + ((6 * 64) << 3));
        wv3_22 = *(const f16x8*)(base + ((10 * 64) << 3));
        wv3_23 = *(const f16x8*)(base + ((14 * 64) << 3));
        wv3_30 = *(const f16x8*)(base + ((3 * 64) << 3));
        wv3_31 = *(const f16x8*)(base + ((7 * 64) << 3));
        wv3_32 = *(const f16x8*)(base + ((11 * 64) << 3));
        wv3_33 = *(const f16x8*)(base + ((15 * 64) << 3));
    }

    // h2 -> sA (silu VALU work covers the F3 prefetch latency)
    #pragma unroll
    for (int nt = 0; nt < 4; ++nt)
        #pragma unroll
        for (int mt = 0; mt < 2; ++mt)
            #pragma unroll
            for (int r = 0; r < 4; ++r) {
                int row = wRow + mt * 16 + lg * 4 + r;
                int col = (wnt + nt) * 16 + lr;
                sA[row * H + (((col >> 3) ^ (row & 7)) << 3) + (col & 7)] =
                    (f16)silu_f(acc[mt][nt][r]);
            }
    __syncthreads();                                 // B7: h2 ready

    // ---- layer 3: pure LDS + prefetched registers ----
    #pragma unroll
    for (int nt = 0; nt < 4; ++nt) {
        float bc = b3[(wnt + nt) * 16 + lr];
        #pragma unroll
        for (int mt = 0; mt < 2; ++mt)
            #pragma unroll
            for (int r = 0; r < 4; ++r)
                acc[mt][nt][r] = bc;
    }
    #pragma unroll
    for (int kk = 0; kk < 4; ++kk) {
        int k = kk * 32 + (lg << 3);
        int slot = (((k >> 3) ^ (lr & 7)) << 3);
        f16x8 a0 = *(const f16x8*)(sA + (wRow + lr) * H + slot);
        f16x8 a1 = *(const f16x8*)(sA + (wRow + 16 + lr) * H + slot);
        f16x8 w0 = (kk == 0) ? wv3_00 : (kk == 1) ? wv3_10 : (kk == 2) ? wv3_20 : wv3_30;
        f16x8 w1 = (kk == 0) ? wv3_01 : (kk == 1) ? wv3_11 : (kk == 2) ? wv3_21 : wv3_31;
        f16x8 w2 = (kk == 0) ? wv3_02 : (kk == 1) ? wv3_12 : (kk == 2) ? wv3_22 : wv3_32;
        f16x8 w3 = (kk == 0) ? wv3_03 : (kk == 1) ? wv3_13 : (kk == 2) ? wv3_23 : wv3_33;
        acc[0][0] = MFMA16(a0, w0, acc[0][0]);
        acc[1][0] = MFMA16(a1, w0, acc[1][0]);
        acc[0][1] = MFMA16(a0, w1, acc[0][1]);
        acc[1][1] = MFMA16(a1, w1, acc[1][1]);
        acc[0][2] = MFMA16(a0, w2, acc[0][2]);
        acc[1][2] = MFMA16(a1, w2, acc[1][2]);
        acc[0][3] = MFMA16(a0, w3, acc[0][3]);
        acc[1][3] = MFMA16(a1, w3, acc[1][3]);
    }

    // ---- store out ----
    #pragma unroll
    for (int mt = 0; mt < 2; ++mt)
        #pragma unroll
        for (int nt = 0; nt < 4; ++nt)
            #pragma unroll
            for (int r = 0; r < 4; ++r) {
                long long row = (long long)R0 + wRow + mt * 16 + lg * 4 + r;
                int col = (wnt + nt) * 16 + lr;
                out[row * H + col] = acc[mt][nt][r];
            }
}

extern "C" void kernel_launch(void* const* d_in, const int* in_sizes, int n_in,
                              void* d_out, int out_size, void* d_ws, size_t ws_size,
                              hipStream_t stream)
{
    const float* x    = (const float*)d_in[0];
    const float* xsc  = (const float*)d_in[1];
    const int*   f2c  = (const int*)d_in[2];
    const float* dist = (const float*)d_in[3];
    const float* W1   = (const float*)d_in[4];
    const float* b1   = (const float*)d_in[5];
    const float* W2   = (const float*)d_in[6];
    const float* b2   = (const float*)d_in[7];
    const float* W3   = (const float*)d_in[8];
    const float* b3   = (const float*)d_in[9];
    f16* ws = (f16*)d_ws;

    prep_w<<<256, 256, 0, stream>>>(W1, W2, W3, ws);

    const int n_rows = 2 * NF;                    // 200000
    dim3 grid(n_rows / TM);                       // 3125
    fused_mlp_v15<<<grid, 256, 0, stream>>>(x, xsc, f2c, dist, W1, b1, b2, b3,
                                            ws, (float*)d_out);
}